// Round 1
// 213.327 us; speedup vs baseline: 1.0581x; 1.0581x over previous
//
#include <hip/hip_runtime.h>
#include <hip/hip_fp16.h>

// Problem constants
#define B_     8
#define NCAM   5
#define J_     15
#define H_     128
#define W_     240
#define NB     128000             // bins = 80*80*20
#define HW_    (H_ * W_)          // 30720
// Overlapping row-pair f16 image: dword[y][x] = (f16 v(y,x), f16 v(y+1,x)),
// y in 0..H-2. Any clamped 2x2 window = dwords (yc,xc),(yc,xc+1): ONE
// ds_read2_b32 per sample (was 2), all 8B useful (was 16B read, 8B used).
#define OV_ROWS (H_ - 1)          // 127
#define OV_DW   (OV_ROWS * W_)    // 30480 dwords
#define SMEM_BYTES (OV_DW * 4)    // 121920 B -> 1 block/CU (16 waves)
#define OV_G4   (OV_DW / 4)       // 7620 uint4 groups
#define TPB    1024
#define NCHUNK 4                  // 480 blocks: 1/CU resident, ~1.875 rounds;
                                  // halves staging work+barriers vs NCHUNK=8
#define BPB    (NB / NCHUNK)      // 32000 bins per block
#define ITEMS  32                 // 32000/1024 = 31.25; last row partially guarded
#define NBJ    (B_ * J_)          // 120
#define NBLK   (NBJ * NCHUNK)     // 480

typedef __fp16 fp16x2 __attribute__((ext_vector_type(2)));

__device__ __forceinline__ unsigned int pkrtz(float lo, float hi) {
    fp16x2 h = __builtin_amdgcn_cvt_pkrtz(lo, hi);  // v_cvt_pkrtz_f16_f32
    return __builtin_bit_cast(unsigned int, h);
}

// Bilinear weights, padding_mode='zeros' validity folded into clamped 2x2
// window (validated R1/R4). Camera-mean 1/5 folded into weights.
// addr16 = yc*W + xc (max 126*240+238 = 30478, fits u16);
// w0pk=(0.2*a0*b0, 0.2*a0*b1) for col xc, w1pk likewise for xc+1 — pair over
// rows (yc, yc+1) matches the overlapping row-pair LDS dword layout.
__device__ __forceinline__ void bilinear_rec(float gx, float gy,
                                             unsigned int& addr,
                                             unsigned int& w0pk,
                                             unsigned int& w1pk) {
    const float ix = (gx + 1.0f) * (0.5f * (W_ - 1));
    const float iy = (gy + 1.0f) * (0.5f * (H_ - 1));
    const float x0f = floorf(ix);
    const float y0f = floorf(iy);
    const float wx1 = ix - x0f, wx0 = 1.0f - wx1;
    const float wy1 = iy - y0f, wy0 = 1.0f - wy1;
    const int x0 = (int)x0f;
    const int y0 = (int)y0f;
    const int xc = min(max(x0, 0), W_ - 2);
    const int yc = min(max(y0, 0), H_ - 2);
    const float vx0 = (x0 >= 0  && x0 <= W_ - 1) ? wx0 : 0.0f;
    const float vx1 = (x0 >= -1 && x0 <= W_ - 2) ? wx1 : 0.0f;
    const float vy0 = (y0 >= 0  && y0 <= H_ - 1) ? wy0 : 0.0f;
    const float vy1 = (y0 >= -1 && y0 <= H_ - 2) ? wy1 : 0.0f;
    const bool xhi = (x0 == W_ - 1);
    const bool xlo = (x0 == -1);
    const bool yhi = (y0 == H_ - 1);
    const bool ylo = (y0 == -1);
    const float a0 = (xhi ? 0.0f : vx0) + (xlo ? vx1 : 0.0f);
    const float a1 = (xhi ? vx0 : 0.0f) + (xlo ? 0.0f : vx1);
    const float b0 = (yhi ? 0.0f : vy0) + (ylo ? vy1 : 0.0f);
    const float b1 = (yhi ? vy0 : 0.0f) + (ylo ? 0.0f : vy1);
    addr = (unsigned int)(yc * W_ + xc);
    w0pk = pkrtz(0.2f * (a0 * b0), 0.2f * (a0 * b1));
    w1pk = pkrtz(0.2f * (a1 * b0), 0.2f * (a1 * b1));
}

__global__ __launch_bounds__(256) void weights_kernel(
    const float* __restrict__ sgrid,          // [NCAM, NB, 2]
    unsigned short* __restrict__ addr16,      // [NCAM*NB]
    uint2* __restrict__ wpk)                  // [NCAM*NB]
{
    const int i = blockIdx.x * 256 + threadIdx.x;
    if (i >= NCAM * NB) return;
    const float2 g = ((const float2*)sgrid)[i];
    unsigned int a, w0, w1;
    bilinear_rec(g.x, g.y, a, w0, w1);
    addr16[i] = (unsigned short)a;
    wpk[i] = make_uint2(w0, w1);
}

// Stage f32 HxW image as overlapping row-pair f16 dwords (121.9 KB).
// dword[y][x] = pk(row_y[x], row_{y+1}[x]); rows 1..126 are read twice from
// L2/L3 (trivial BW), each uint4 group covers 4 consecutive x.
__device__ __forceinline__ void stage_overlap(const float* __restrict__ img,
                                              unsigned int* s_img, int tid) {
    const float4* __restrict__ src4 = (const float4*)img;  // 60 groups per row
    uint4* dst = (uint4*)s_img;
    for (int gi = tid; gi < OV_G4; gi += TPB) {
        const int y  = gi / 60;
        const int xg = gi - y * 60;
        const float4 t = src4[y * 60 + xg];        // row y
        const float4 b = src4[y * 60 + 60 + xg];   // row y+1
        uint4 d;
        d.x = pkrtz(t.x, b.x);
        d.y = pkrtz(t.y, b.y);
        d.z = pkrtz(t.z, b.z);
        d.w = pkrtz(t.w, b.w);
        dst[gi] = d;
    }
}

// One bilinear sample: single ds_read2_b32, no perm/odd handling.
__device__ __forceinline__ float sample_ov(const unsigned int* s_img,
                                           unsigned int a16,
                                           unsigned int w0, unsigned int w1) {
    const unsigned int* base = s_img + a16;
    const unsigned int d0 = base[0];               // (v(yc,xc),   v(yc+1,xc))
    const unsigned int d1 = base[1];               // (v(yc,xc+1), v(yc+1,xc+1))
    __half2 p = __hmul2(__builtin_bit_cast(__half2, d0),
                        __builtin_bit_cast(__half2, w0));
    p = __hfma2(__builtin_bit_cast(__half2, d1),
                __builtin_bit_cast(__half2, w1), p);
    return __low2float(p) + __high2float(p);
}

// 1 block/CU (121.9 KB LDS, 16 waves). min 4 waves/EU -> VGPR cap 128 so the
// compiler can pipeline the 32 independent items (old kernel sat at 32 VGPRs).
__global__ __launch_bounds__(TPB, 4) void project_kernel(
    const float* __restrict__ hm,             // [B, NCAM, J, H, W]
    const unsigned short* __restrict__ addr16,
    const uint2* __restrict__ wpk,
    float* __restrict__ out)                  // [B, J, NB]
{
    extern __shared__ unsigned int s_img[];   // OV_DW dwords
    const int tid   = threadIdx.x;
    // bj-major mapping: same-bj blocks at bids bj+120k; 120%8==0 -> same XCD,
    // so all 4 chunks of a (b,j) share one XCD's L2 for the staged images.
    const int bj    = blockIdx.x % NBJ;
    const int chunk = blockIdx.x / NBJ;
    const int b     = bj / J_;
    const int j     = bj % J_;
    const int bin0  = chunk * BPB;

    float acc[ITEMS];
#pragma unroll
    for (int it = 0; it < ITEMS; ++it) acc[it] = 0.0f;

    for (int n = 0; n < NCAM; ++n) {
        __syncthreads();
        stage_overlap(hm + (((size_t)b * NCAM + n) * J_ + j) * HW_, s_img, tid);
        __syncthreads();
        const unsigned short* __restrict__ ap = addr16 + n * NB + bin0;
        const uint2* __restrict__ wp = wpk + n * NB + bin0;
#pragma unroll
        for (int it = 0; it < ITEMS; ++it) {
            const int r = it * TPB + tid;     // coalesced
            if (r < BPB) {                    // last item partial (32000 = 31*1024+256)
                acc[it] += sample_ov(s_img, ap[r], wp[r].x, wp[r].y);
            }
        }
    }

    float* __restrict__ o = out + (size_t)bj * NB + bin0;
#pragma unroll
    for (int it = 0; it < ITEMS; ++it) {
        const int r = it * TPB + tid;
        if (r < BPB) o[r] = fminf(fmaxf(acc[it], 0.0f), 1.0f);  // 1/5 in weights
    }
}

// Fallback (tiny ws): R1-style f32-LDS kernel, inline weights. 600 blocks.
#define FB_SMEM   (HW_ * 4)
#define FB_NCHUNK 5
#define FB_BPB    (NB / FB_NCHUNK)   // 25600
#define FB_ITEMS  (FB_BPB / TPB)     // 25
__global__ __launch_bounds__(TPB) void project_fallback(
    const float* __restrict__ hm,
    const float* __restrict__ sgrid,
    float* __restrict__ out)
{
    extern __shared__ float s_f32[];
    const int tid   = threadIdx.x;
    const int bj    = blockIdx.x % NBJ;
    const int chunk = blockIdx.x / NBJ;
    const int b     = bj / J_;
    const int j     = bj % J_;
    const int bin0  = chunk * FB_BPB;

    float acc[FB_ITEMS];
#pragma unroll
    for (int it = 0; it < FB_ITEMS; ++it) acc[it] = 0.0f;

    for (int n = 0; n < NCAM; ++n) {
        __syncthreads();
        const float4* __restrict__ src =
            (const float4*)(hm + (((size_t)b * NCAM + n) * J_ + j) * HW_);
        float4* dst = (float4*)s_f32;
        for (int i = tid; i < HW_ / 4; i += TPB) dst[i] = src[i];
        __syncthreads();
        const float2* __restrict__ g2 = (const float2*)sgrid + n * NB + bin0;
#pragma unroll
        for (int it = 0; it < FB_ITEMS; ++it) {
            const float2 g = g2[it * TPB + tid];
            const float ix = (g.x + 1.0f) * (0.5f * (W_ - 1));
            const float iy = (g.y + 1.0f) * (0.5f * (H_ - 1));
            const float x0f = floorf(ix), y0f = floorf(iy);
            const float wx1 = ix - x0f, wx0 = 1.0f - wx1;
            const float wy1 = iy - y0f, wy0 = 1.0f - wy1;
            const int x0 = (int)x0f, y0 = (int)y0f;
            const int xc = min(max(x0, 0), W_ - 2);
            const int yc = min(max(y0, 0), H_ - 2);
            const float vx0 = (x0 >= 0  && x0 <= W_ - 1) ? wx0 : 0.0f;
            const float vx1 = (x0 >= -1 && x0 <= W_ - 2) ? wx1 : 0.0f;
            const float vy0 = (y0 >= 0  && y0 <= H_ - 1) ? wy0 : 0.0f;
            const float vy1 = (y0 >= -1 && y0 <= H_ - 2) ? wy1 : 0.0f;
            const bool xhi = (x0 == W_ - 1), xlo = (x0 == -1);
            const bool yhi = (y0 == H_ - 1), ylo = (y0 == -1);
            const float a0 = (xhi ? 0.0f : vx0) + (xlo ? vx1 : 0.0f);
            const float a1 = (xhi ? vx0 : 0.0f) + (xlo ? 0.0f : vx1);
            const float b0 = (yhi ? 0.0f : vy0) + (ylo ? vy1 : 0.0f);
            const float b1 = (yhi ? vy0 : 0.0f) + (ylo ? 0.0f : vy1);
            const float* r0 = s_f32 + (yc * W_ + xc);
            acc[it] += b0 * (a0 * r0[0] + a1 * r0[1])
                     + b1 * (a0 * r0[W_] + a1 * r0[W_ + 1]);
        }
    }
    float* __restrict__ o = out + (size_t)bj * NB + bin0;
#pragma unroll
    for (int it = 0; it < FB_ITEMS; ++it)
        o[it * TPB + tid] = fminf(fmaxf(acc[it] * 0.2f, 0.0f), 1.0f);
}

extern "C" void kernel_launch(void* const* d_in, const int* in_sizes, int n_in,
                              void* d_out, int out_size, void* d_ws, size_t ws_size,
                              hipStream_t stream) {
    const float* hm = (const float*)d_in[0];   // [8,5,15,128,240] f32
    const float* sg = (const float*)d_in[1];   // [5,128000,2] f32
    float* out = (float*)d_out;                // [8,15,128000] f32

    (void)hipFuncSetAttribute((const void*)project_kernel,
                              hipFuncAttributeMaxDynamicSharedMemorySize, SMEM_BYTES);
    (void)hipFuncSetAttribute((const void*)project_fallback,
                              hipFuncAttributeMaxDynamicSharedMemorySize, FB_SMEM);

    const size_t addr_bytes = (size_t)NCAM * NB * sizeof(unsigned short); // 1.28 MB
    const size_t wpk_bytes  = (size_t)NCAM * NB * sizeof(uint2);          // 5.12 MB
    if (ws_size >= addr_bytes + wpk_bytes) {
        unsigned short* addr16 = (unsigned short*)d_ws;
        uint2* wpk = (uint2*)((char*)d_ws + addr_bytes);
        weights_kernel<<<(NCAM * NB + 255) / 256, 256, 0, stream>>>(sg, addr16, wpk);
        project_kernel<<<NBLK, TPB, SMEM_BYTES, stream>>>(hm, addr16, wpk, out);
    } else {
        project_fallback<<<NBJ * FB_NCHUNK, TPB, FB_SMEM, stream>>>(hm, sg, out);
    }
}